// Round 3
// baseline (2843.646 us; speedup 1.0000x reference)
//
#include <hip/hip_runtime.h>
#include <hip/hip_bf16.h>
#include <math.h>

// ---- problem constants (BERT-base, B=8, S=512) ----
#define S_LEN   512
#define HID     768
#define NLAYER  12
#define NHEAD   12
#define FFN_DIM 3072
#define HDIM    64
#define NTOK    4096   // B*S
#define QKVN    2304   // 3*HID

typedef __bf16 bf16x8 __attribute__((ext_vector_type(8)));
typedef __bf16 bf16x4 __attribute__((ext_vector_type(4)));
typedef float  f32x4  __attribute__((ext_vector_type(4)));

typedef __attribute__((address_space(1))) const unsigned int gas_u32;
typedef __attribute__((address_space(3))) unsigned int las_u32;

#define MFMA16(a, b, c) __builtin_amdgcn_mfma_f32_16x16x32_bf16((a), (b), (c), 0, 0, 0)

// ---------------------------------------------------------------------------
// fast exact-erf GELU: A&S 7.1.26, max abs err 1.5e-7 (invisible in bf16).
// ---------------------------------------------------------------------------
__device__ __forceinline__ float fast_gelu(float v) {
  float ax = fabsf(v) * 0.70710678118654752f;
  float t  = __builtin_amdgcn_rcpf(fmaf(0.3275911f, ax, 1.0f));
  float p  = fmaf(fmaf(fmaf(fmaf(1.061405429f, t, -1.453152027f), t,
                            1.421413741f), t, -0.284496736f), t, 0.254829592f);
  float e  = __expf(-ax * ax);
  float er = 1.0f - p * t * e;
  er = copysignf(er, v);
  return 0.5f * v * (1.0f + er);
}

// ---------------------------------------------------------------------------
// block-wide reduction of (sum, sumsq) over 256 threads (4 waves of 64)
// ---------------------------------------------------------------------------
__device__ __forceinline__ void block_reduce_2(float& sum, float& sq) {
  __shared__ float sd[8];
  int lane = threadIdx.x & 63;
  int wid  = threadIdx.x >> 6;
  #pragma unroll
  for (int off = 32; off > 0; off >>= 1) {
    sum += __shfl_down(sum, off, 64);
    sq  += __shfl_down(sq,  off, 64);
  }
  if (lane == 0) { sd[wid] = sum; sd[4 + wid] = sq; }
  __syncthreads();
  sum = sd[0] + sd[1] + sd[2] + sd[3];
  sq  = sd[4] + sd[5] + sd[6] + sd[7];
}

// ---------------------------------------------------------------------------
// mask bias: -10000 where input_id == 0 (padding), else 0
// ---------------------------------------------------------------------------
__global__ __launch_bounds__(256) void mask_kernel(const int* __restrict__ ids,
                                                   float* __restrict__ mb) {
  int i = blockIdx.x * 256 + threadIdx.x;
  if (i < NTOK) mb[i] = (ids[i] == 0) ? -10000.0f : 0.0f;
}

// ---------------------------------------------------------------------------
// pack q/k/v biases for ALL layers into [L][2304] once
// ---------------------------------------------------------------------------
__global__ __launch_bounds__(256) void pack_qkvb_kernel(
    const float* __restrict__ bq, const float* __restrict__ bk,
    const float* __restrict__ bv, float* __restrict__ out) {
  int i = blockIdx.x * 256 + threadIdx.x;
  if (i >= NLAYER * QKVN) return;
  int l = i / QKVN, c = i % QKVN;
  float v = (c < HID) ? bq[l * HID + c]
          : (c < 2 * HID) ? bk[l * HID + c - HID]
                          : bv[l * HID + c - 2 * HID];
  out[i] = v;
}

// ---------------------------------------------------------------------------
// embeddings + layernorm -> fp32 h and bf16 h
// ---------------------------------------------------------------------------
__global__ __launch_bounds__(256) void embed_ln_kernel(
    const int* __restrict__ ids, const int* __restrict__ tids,
    const float* __restrict__ we, const float* __restrict__ pe,
    const float* __restrict__ te, const float* __restrict__ gamma,
    const float* __restrict__ beta, float* __restrict__ out32,
    __bf16* __restrict__ out16) {
  int t = blockIdx.x;
  int s = t & (S_LEN - 1);
  int id = ids[t];
  int tp = tids[t];
  float x[3];
  #pragma unroll
  for (int i = 0; i < 3; ++i) {
    int c = threadIdx.x + i * 256;
    x[i] = we[(size_t)id * HID + c] + pe[(size_t)s * HID + c] +
           te[(size_t)tp * HID + c];
  }
  float sum = x[0] + x[1] + x[2];
  float sq  = x[0]*x[0] + x[1]*x[1] + x[2]*x[2];
  block_reduce_2(sum, sq);
  float mu   = sum * (1.0f / HID);
  float var  = sq * (1.0f / HID) - mu * mu;
  float rstd = rsqrtf(var + 1e-12f);
  #pragma unroll
  for (int i = 0; i < 3; ++i) {
    int c = threadIdx.x + i * 256;
    float v = (x[i] - mu) * rstd * gamma[c] + beta[c];
    out32[(size_t)t * HID + c] = v;
    out16[(size_t)t * HID + c] = (__bf16)v;
  }
}

// ---------------------------------------------------------------------------
// residual add (+ optional third partial) + layernorm -> fp32 and bf16
// ---------------------------------------------------------------------------
__global__ __launch_bounds__(256) void add_ln_kernel(
    const float* __restrict__ a, const float* __restrict__ b,
    const float* __restrict__ c,
    const float* __restrict__ gamma, const float* __restrict__ beta,
    float* __restrict__ out32, __bf16* __restrict__ out16) {
  int t = blockIdx.x;
  float x[3];
  #pragma unroll
  for (int i = 0; i < 3; ++i) {
    int ci = threadIdx.x + i * 256;
    size_t idx = (size_t)t * HID + ci;
    x[i] = a[idx] + b[idx];
    if (c) x[i] += c[idx];
  }
  float sum = x[0] + x[1] + x[2];
  float sq  = x[0]*x[0] + x[1]*x[1] + x[2]*x[2];
  block_reduce_2(sum, sq);
  float mu   = sum * (1.0f / HID);
  float var  = sq * (1.0f / HID) - mu * mu;
  float rstd = rsqrtf(var + 1e-12f);
  #pragma unroll
  for (int i = 0; i < 3; ++i) {
    int ci = threadIdx.x + i * 256;
    float v = (x[i] - mu) * rstd * gamma[ci] + beta[ci];
    out32[(size_t)t * HID + ci] = v;
    out16[(size_t)t * HID + ci] = (__bf16)v;
  }
}

// ---------------------------------------------------------------------------
// transpose + fp32->bf16: src [R][C] f32 -> dst [C][R] bf16. blockIdx.z=layer.
// ---------------------------------------------------------------------------
__global__ __launch_bounds__(256) void tcvt_kernel(
    const float* __restrict__ src, __bf16* __restrict__ dst, int R, int C) {
  __shared__ float tile[32][33];
  int l = blockIdx.z;
  src += (size_t)l * R * C;
  dst += (size_t)l * R * C;
  int c0 = blockIdx.x * 32, r0 = blockIdx.y * 32;
  int tx = threadIdx.x & 31, ty = threadIdx.x >> 5;  // ty 0..7
  #pragma unroll
  for (int i = 0; i < 4; ++i) {
    int r = ty + i * 8;
    tile[r][tx] = src[(size_t)(r0 + r) * C + c0 + tx];
  }
  __syncthreads();
  #pragma unroll
  for (int i = 0; i < 4; ++i) {
    int r = ty + i * 8;
    dst[(size_t)(c0 + r) * R + r0 + tx] = (__bf16)tile[tx][r];
  }
}

// 4 HxH transposes (wq,wk,wv,wo), blockIdx.z = layer*4 + sel.
__global__ __launch_bounds__(256) void tcvt4_kernel(
    const float* __restrict__ sq, const float* __restrict__ sk,
    const float* __restrict__ sv, const float* __restrict__ so,
    __bf16* __restrict__ dqkv, __bf16* __restrict__ dwo) {
  __shared__ float tile[32][33];
  const size_t WHH = (size_t)HID * HID;
  int z = blockIdx.z;
  int l = z >> 2, sel = z & 3;
  const float* src = ((sel == 0) ? sq : (sel == 1) ? sk : (sel == 2) ? sv : so)
                     + (size_t)l * WHH;
  __bf16* dst = (sel < 3) ? dqkv + (size_t)l * 3 * WHH + (size_t)sel * WHH
                          : dwo + (size_t)l * WHH;
  int c0 = blockIdx.x * 32, r0 = blockIdx.y * 32;
  int tx = threadIdx.x & 31, ty = threadIdx.x >> 5;
  #pragma unroll
  for (int i = 0; i < 4; ++i) {
    int r = ty + i * 8;
    tile[r][tx] = src[(size_t)(r0 + r) * HID + c0 + tx];
  }
  __syncthreads();
  #pragma unroll
  for (int i = 0; i < 4; ++i) {
    int r = ty + i * 8;
    dst[(size_t)(c0 + r) * HID + r0 + tx] = (__bf16)tile[tx][r];
  }
}

// ---------------------------------------------------------------------------
// m97-style bf16 MFMA GEMM (kept for WO / FFN2 split-K; proven path).
// ---------------------------------------------------------------------------
template <int MODE, int TN>
__global__ __launch_bounds__(256) void mfma_gemm(
    const __bf16* __restrict__ A, const __bf16* __restrict__ Bt,
    const float* __restrict__ bias, void* __restrict__ Cout,
    __bf16* __restrict__ vtout, int M, int N, int K, int kchunk) {
  constexpr int AI = 4;
  constexpr int BI = TN / 32;
  constexpr int RT = (TN == 128) ? 4 : 2;
  constexpr int CT = 4;
  __shared__ __align__(16) __bf16 As[128 * 64];
  __shared__ __align__(16) __bf16 Bs[TN * 64];
  const int tid = threadIdx.x;
  const int w = tid >> 6, lane = tid & 63;
  const int l15 = lane & 15, quad = lane >> 4;
  const int m0 = blockIdx.y * 128, n0 = blockIdx.x * TN;
  const int kz = blockIdx.z;
  const int lr = lane >> 3;
  const int colg = (lane & 7) ^ lr;

  const int wr = (TN == 128) ? (w >> 1) * 64 : w * 32;
  const int wc = (TN == 128) ? (w & 1) * 64 : 0;

  A  += (size_t)kz * kchunk;
  Bt += (size_t)kz * kchunk;

  f32x4 acc[RT][CT];
  const f32x4 z4 = {0.f, 0.f, 0.f, 0.f};
  #pragma unroll
  for (int i = 0; i < RT; ++i)
    #pragma unroll
    for (int j = 0; j < CT; ++j) acc[i][j] = z4;

  const __bf16* Ag = A  + (size_t)(m0 + 8 * AI * w + lr) * K + colg * 8;
  const __bf16* Bg = Bt + (size_t)(n0 + 8 * BI * w + lr) * K + colg * 8;
  __bf16* Al = As + 512 * AI * w;
  __bf16* Bl = Bs + 512 * BI * w;

  for (int kt = 0; kt < kchunk; kt += 64) {
    #pragma unroll
    for (int i = 0; i < AI; ++i)
      __builtin_amdgcn_global_load_lds(
          (gas_u32*)(Ag + (size_t)(8 * i) * K + kt),
          (las_u32*)(Al + 512 * i), 16, 0, 0);
    #pragma unroll
    for (int i = 0; i < BI; ++i)
      __builtin_amdgcn_global_load_lds(
          (gas_u32*)(Bg + (size_t)(8 * i) * K + kt),
          (las_u32*)(Bl + 512 * i), 16, 0, 0);
    __syncthreads();
    #pragma unroll
    for (int kc = 0; kc < 2; ++kc) {
      bf16x8 af[RT], bfr[CT];
      #pragma unroll
      for (int rt = 0; rt < RT; ++rt) {
        int row = wr + rt * 16 + l15;
        af[rt] = *(const bf16x8*)&As[(row * 8 + ((kc * 4 + quad) ^ (row & 7))) * 8];
      }
      #pragma unroll
      for (int ct = 0; ct < CT; ++ct) {
        int col = wc + ct * 16 + l15;
        bfr[ct] = *(const bf16x8*)&Bs[(col * 8 + ((kc * 4 + quad) ^ (col & 7))) * 8];
      }
      #pragma unroll
      for (int rt = 0; rt < RT; ++rt)
        #pragma unroll
        for (int ct = 0; ct < CT; ++ct)
          acc[rt][ct] = MFMA16(af[rt], bfr[ct], acc[rt][ct]);
    }
    __syncthreads();
  }

  float* outf = (float*)Cout + (size_t)kz * M * N;
  #pragma unroll
  for (int rt = 0; rt < RT; ++rt) {
    int rbase = m0 + wr + rt * 16 + quad * 4;
    #pragma unroll
    for (int ct = 0; ct < CT; ++ct) {
      int col = n0 + wc + ct * 16 + l15;
      float bv = (kz == 0) ? bias[col] : 0.0f;
      float vv[4];
      #pragma unroll
      for (int r = 0; r < 4; ++r) {
        float v = acc[rt][ct][r] + bv;
        if (MODE == 2) v = fast_gelu(v);
        vv[r] = v;
      }
      if (MODE == 3 && col >= 2 * HID) {
        int cc = col - 2 * HID;
        int hh = cc >> 6, d = cc & 63;
        int bb = rbase >> 9, s0 = rbase & (S_LEN - 1);
        bf16x4 pk = {(__bf16)vv[0], (__bf16)vv[1], (__bf16)vv[2], (__bf16)vv[3]};
        *(bf16x4*)(vtout +
                   (((size_t)(bb * NHEAD + hh) * HDIM + d) * S_LEN + s0)) = pk;
      } else {
        #pragma unroll
        for (int r = 0; r < 4; ++r) {
          if (MODE == 0)
            outf[(size_t)(rbase + r) * N + col] = vv[r];
          else
            ((__bf16*)Cout)[(size_t)(rbase + r) * N + col] = (__bf16)vv[r];
        }
      }
    }
  }
}

// ---------------------------------------------------------------------------
// 256x256 8-phase bf16 GEMM (m201-template port): C = A[M,K] @ Bt[N,K]^T+bias.
// 512 threads = 8 waves (2M x 4N), per-wave 128x64 output, BK=64, double-
// buffered LDS (128 KiB), raw s_barrier + counted vmcnt (never 0 mid-loop),
// setprio(1) around each 16-MFMA quadrant.
// Staging/read swizzle identical to mfma_gemm (verified): source col chunk
// pre-XOR (l&7)^(l>>3); read col chunk (kc*4+quad)^(row&7).
// Stage schedule per iter (tiles T0=2i->buf0 p1-4, T1=2i+1->buf1 p5-8):
//   p1:T1.Ah0  p2:T1.Ah1  p3:T2.Bh0  p4:T2.Bh1  p5:T2.Ah0  p6:T2.Ah1
//   p7:T3.Bh0  p8:T3.Bh1   (T2,T3 guarded < NT)
// Gates: vmcnt(4) before trailing barrier at p4 & p8 (last iter: p4->vmcnt(0)).
// FIFO check: at p4-gate, retired = prev T1.B + T1.A -> buf1 complete for p5;
// at p8-gate, retired = T2.B + T2.A -> buf0 complete for next p1.
// MODE 2: +fast GELU; MODE 3: V-cols (>=1536) -> vt[b][h][d][s].
// ---------------------------------------------------------------------------
#define BARX __builtin_amdgcn_s_barrier()
#define LGKM0 do { asm volatile("s_waitcnt lgkmcnt(0)" ::: "memory"); \
                   __builtin_amdgcn_sched_barrier(0); } while (0)
#define VMCNT4 do { asm volatile("s_waitcnt vmcnt(4)" ::: "memory"); \
                    __builtin_amdgcn_sched_barrier(0); } while (0)
#define VMCNT0 do { asm volatile("s_waitcnt vmcnt(0)" ::: "memory"); \
                    __builtin_amdgcn_sched_barrier(0); } while (0)
#define PRIO1 __builtin_amdgcn_s_setprio(1)
#define PRIO0 __builtin_amdgcn_s_setprio(0)

#define G_LDS(src, dst) \
  __builtin_amdgcn_global_load_lds((gas_u32*)(src), (las_u32*)(dst), 16, 0, 0)

// stage half h (0/1) of K-tile t of A/B into buffer bb (2 insts, all 8 waves)
#define STAGE_A(bb, h, t) do {                                              \
  G_LDS(Asrc + (size_t)((h)*128 + wv8) * Ksz + (size_t)(t)*64,              \
        &As[bb][(h)*8192 + wv512]);                                         \
  G_LDS(Asrc + (size_t)((h)*128 + 64 + wv8) * Ksz + (size_t)(t)*64,         \
        &As[bb][(h)*8192 + 4096 + wv512]);                                  \
} while (0)
#define STAGE_B(bb, h, t) do {                                              \
  G_LDS(Bsrc + (size_t)((h)*128 + wv8) * Ksz + (size_t)(t)*64,              \
        &Bs[bb][(h)*8192 + wv512]);                                         \
  G_LDS(Bsrc + (size_t)((h)*128 + 64 + wv8) * Ksz + (size_t)(t)*64,         \
        &Bs[bb][(h)*8192 + 4096 + wv512]);                                  \
} while (0)

// read 4 A-frags (rows (fmo..fmo+3)*16+l15 of this wave's half), both kc
#define RD_A(bb, fmo, dst) do {                                             \
  _Pragma("unroll") for (int f = 0; f < 4; ++f) {                           \
    dst[f][0] = *(const bf16x8*)&As[bb][aoff + ((fmo) + f) * 1024 + xr0];   \
    dst[f][1] = *(const bf16x8*)&As[bb][aoff + ((fmo) + f) * 1024 + xr1];   \
  } } while (0)
#define RD_B(bb, fno, dst) do {                                             \
  _Pragma("unroll") for (int f = 0; f < 2; ++f) {                           \
    dst[f][0] = *(const bf16x8*)&Bs[bb][boff + ((fno) + f) * 1024 + xr0];   \
    dst[f][1] = *(const bf16x8*)&Bs[bb][boff + ((fno) + f) * 1024 + xr1];   \
  } } while (0)

// 16-MFMA quadrant: acc[mo..mo+3][no..no+1]
#define MMQ(am, bn, mo, no) do {                                            \
  _Pragma("unroll") for (int f = 0; f < 4; ++f)                             \
  _Pragma("unroll") for (int g = 0; g < 2; ++g) {                           \
    acc[(mo) + f][(no) + g] = MFMA16(am[f][0], bn[g][0], acc[(mo)+f][(no)+g]); \
    acc[(mo) + f][(no) + g] = MFMA16(am[f][1], bn[g][1], acc[(mo)+f][(no)+g]); \
  } } while (0)

template <int MODE>
__global__ __launch_bounds__(512, 2) void mfma_gemm256(
    const __bf16* __restrict__ A, const __bf16* __restrict__ Bt,
    const float* __restrict__ bias, void* __restrict__ Cout,
    __bf16* __restrict__ vtout, int M, int N, int K) {
  __shared__ __align__(16) __bf16 As[2][256 * 64];
  __shared__ __align__(16) __bf16 Bs[2][256 * 64];
  const int tid = threadIdx.x;
  const int w = tid >> 6, lane = tid & 63;
  const int l15 = lane & 15, quad = lane >> 4;
  const int wm = w >> 2, wn = w & 3;
  const int m0 = blockIdx.y * 256, n0 = blockIdx.x * 256;
  const int lr = lane >> 3;
  const int colg = ((lane & 7) ^ lr) * 8;
  const int wv8 = w * 8, wv512 = w * 512;
  const size_t Ksz = K;

  // read-address constants (elem offsets within a 128x64 half)
  const int aoff = wm * 8192 + l15 * 64;
  const int boff = (wn >> 1) * 8192 + (wn & 1) * 4096 + l15 * 64;
  const int xr0 = (quad ^ (l15 & 7)) * 8;
  const int xr1 = xr0 ^ 32;  // chunk (quad+4)^(l15&7), *8

  const __bf16* Asrc = A  + (size_t)(m0 + lr) * Ksz + colg;
  const __bf16* Bsrc = Bt + (size_t)(n0 + lr) * Ksz + colg;

  f32x4 acc[8][4];
  const f32x4 z4 = {0.f, 0.f, 0.f, 0.f};
  #pragma unroll
  for (int i = 0; i < 8; ++i)
    #pragma unroll
    for (int j = 0; j < 4; ++j) acc[i][j] = z4;

  const int NT = K >> 6;   // K-tiles (BK=64); K % 128 == 0
  const int NI = NT >> 1;  // iterations (2 K-tiles each)

  // ---- prologue: T0 full (buf0) + T1.B halves (buf1); 12 insts in flight
  STAGE_B(0, 0, 0); STAGE_B(0, 1, 0);
  STAGE_A(0, 0, 0); STAGE_A(0, 1, 0);
  STAGE_B(1, 0, 1); STAGE_B(1, 1, 1);
  VMCNT4;  // T0's 8 insts landed; T1.B's 4 may fly
  BARX;

  bf16x8 aL[4][2], aH[4][2], bL[2][2], bH[2][2];

  for (int i = 0; i < NI; ++i) {
    const int T1 = 2 * i + 1, T2 = 2 * i + 2, T3 = 2 * i + 3;
    const bool s2 = (T2 < NT), s3 = (T3 < NT), last = (i == NI - 1);

    // ---- phase 1: buf0 A-lo + B-lo reads; stage T1.Ah0 -> buf1
    RD_A(0, 0, aL); RD_B(0, 0, bL);
    STAGE_A(1, 0, T1);
    BARX; LGKM0; PRIO1; MMQ(aL, bL, 0, 0); PRIO0; BARX;
    // ---- phase 2: buf0 B-hi reads; stage T1.Ah1
    RD_B(0, 2, bH);
    STAGE_A(1, 1, T1);
    BARX; LGKM0; PRIO1; MMQ(aL, bH, 0, 2); PRIO0; BARX;
    // ---- phase 3: buf0 A-hi reads; stage T2.Bh0 -> buf0
    RD_A(0, 4, aH);
    if (s2) STAGE_B(0, 0, T2);
    BARX; LGKM0; PRIO1; MMQ(aH, bH, 4, 2); PRIO0; BARX;
    // ---- phase 4: no reads; stage T2.Bh1; gate T1.A landed
    if (s2) STAGE_B(0, 1, T2);
    BARX; PRIO1; MMQ(aH, bL, 4, 0); PRIO0;
    if (last) { VMCNT0; } else { VMCNT4; }
    BARX;
    // ---- phase 5: buf1 A-lo + B-lo reads; stage T2.Ah0 -> buf0
    RD_A(1, 0, aL); RD_B(1, 0, bL);
    if (s2) STAGE_A(0, 0, T2);
    BARX; LGKM0; PRIO1; MMQ(aL, bL, 0, 0); PRIO0; BARX;
    // ---- phase 6: buf1 B-hi reads; stage T2.Ah1
    RD_B(1, 2, bH);
    if (s2) STAGE_A(0, 1, T2);
    BARX; LGKM0; PRIO1; MMQ(aL, bH, 0, 2); PRIO0; BARX;
    // ---- phase 7: buf1 A-hi reads; stage T3.Bh0 -> buf1
    RD_A(1, 4, aH);
    if (s3) STAGE_B(1, 0, T3);
    BARX; LGKM0; PRIO1; MMQ(aH, bH, 4, 2); PRIO0; BARX;
    // ---- phase 8: no reads; stage T3.Bh1; gate T2 landed
    if (s3) STAGE_B(1, 1, T3);
    BARX; PRIO1; MMQ(aH, bL, 4, 0); PRIO0;
    if (!last) { VMCNT4; }
    BARX;
  }

  // ---- epilogue ----
  #pragma unroll
  for (int fm = 0; fm < 8; ++fm) {
    int rbase = m0 + wm * 128 + fm * 16 + quad * 4;
    #pragma unroll
    for (int fn = 0; fn < 4; ++fn) {
      int col = n0 + wn * 64 + fn * 16 + l15;
      float bv = bias[col];
      float vv[4];
      #pragma unroll
      for (int r = 0; r < 4; ++r) {
        float v = acc[fm][fn][r] + bv;
        if (MODE == 2) v = fast_gelu(v);
        vv[r] = v;
      }
      if (MODE == 3 && col >= 2 * HID) {
        int cc = col - 2 * HID;
        int hh = cc >> 6, d = cc & 63;
        int bb = rbase >> 9, s0 = rbase & (S_LEN - 1);
        bf16x4 pk = {(__bf16)vv[0], (__bf16)vv[1], (__bf16)vv[2], (__bf16)vv[3]};
        *(bf16x4*)(vtout +
                   (((size_t)(bb * NHEAD + hh) * HDIM + d) * S_LEN + s0)) = pk;
      } else {
        #pragma unroll
        for (int r = 0; r < 4; ++r)
          ((__bf16*)Cout)[(size_t)(rbase + r) * N + col] = (__bf16)vv[r];
      }
    }
  }
}

// ---------------------------------------------------------------------------
// MFMA attention: block = (64 q-rows, head, batch); wave w owns 16 q-rows.
// ---------------------------------------------------------------------------
__global__ __launch_bounds__(256) void attn_mfma(
    const __bf16* __restrict__ qkv,  // [tok][2304], q at +0, k at +768
    const __bf16* __restrict__ vt,   // [b][h][64][512]
    const float* __restrict__ mb,    // [B*S]
    __bf16* __restrict__ ctx) {      // [tok][768]
  constexpr int PLD = 264;
  __shared__ __align__(16) __bf16 Plds[4][16 * PLD];
  const int tid = threadIdx.x;
  const int wv = tid >> 6, lane = tid & 63;
  const int l15 = lane & 15, quad = lane >> 4;
  const int b = blockIdx.z, hh = blockIdx.y, q0 = blockIdx.x * 64;
  const f32x4 z4 = {0.f, 0.f, 0.f, 0.f};

  size_t qoff = ((size_t)(b * S_LEN) + q0 + wv * 16 + l15) * QKVN + hh * HDIM;
  bf16x8 qa0 = *(const bf16x8*)(qkv + qoff + quad * 8);
  bf16x8 qa1 = *(const bf16x8*)(qkv + qoff + 32 + quad * 8);

  f32x4 sc[32];
  #pragma unroll
  for (int kt = 0; kt < 32; ++kt) {
    size_t koff = ((size_t)(b * S_LEN) + kt * 16 + l15) * QKVN + HID + hh * HDIM;
    bf16x8 kb0 = *(const bf16x8*)(qkv + koff + quad * 8);
    bf16x8 kb1 = *(const bf16x8*)(qkv + koff + 32 + quad * 8);
    f32x4 t = MFMA16(qa0, kb0, z4);
    sc[kt] = MFMA16(qa1, kb1, t);
  }

  float mx[4] = {-1e30f, -1e30f, -1e30f, -1e30f};
  #pragma unroll
  for (int kt = 0; kt < 32; ++kt) {
    float mval = mb[b * S_LEN + kt * 16 + l15];
    #pragma unroll
    for (int r = 0; r < 4; ++r) {
      float x = sc[kt][r] * 0.125f + mval;
      sc[kt][r] = x;
      mx[r] = fmaxf(mx[r], x);
    }
  }
  #pragma unroll
  for (int m = 1; m < 16; m <<= 1)
    #pragma unroll
    for (int r = 0; r < 4; ++r) mx[r] = fmaxf(mx[r], __shfl_xor(mx[r], m, 64));

  float sm[4] = {0.f, 0.f, 0.f, 0.f};
  #pragma unroll
  for (int kt = 0; kt < 32; ++kt)
    #pragma unroll
    for (int r = 0; r < 4; ++r) {
      float e = __expf(sc[kt][r] - mx[r]);
      sc[kt][r] = e;
      sm[r] += e;
    }
  #pragma unroll
  for (int m = 1; m < 16; m <<= 1)
    #pragma unroll
    for (int r = 0; r < 4; ++r) sm[r] += __shfl_xor(sm[r], m, 64);
  float inv[4];
  #pragma unroll
  for (int r = 0; r < 4; ++r) inv[r] = 1.0f / sm[r];

  __bf16* pbuf = &Plds[wv][0];
  const __bf16* vbase = vt + (size_t)(b * NHEAD + hh) * HDIM * S_LEN;
  f32x4 oc[4] = {z4, z4, z4, z4};
  #pragma unroll
  for (int half = 0; half < 2; ++half) {
    #pragma unroll
    for (int kt2 = 0; kt2 < 16; ++kt2) {
      int kt = half * 16 + kt2;
      #pragma unroll
      for (int r = 0; r < 4; ++r)
        pbuf[(quad * 4 + r) * PLD + kt2 * 16 + l15] = (__bf16)(sc[kt][r] * inv[r]);
    }
    #pragma unroll
    for (int kc = 0; kc < 8; ++kc) {
      bf16x8 pa = *(const bf16x8*)&pbuf[l15 * PLD + kc * 32 + quad * 8];
      int kbase = half * 256 + kc * 32;
      #pragma unroll
      for (int ct = 0; ct < 4; ++ct) {
        const __bf16* vp =
            vbase + (size_t)(ct * 16 + l15) * S_LEN + kbase + quad * 8;
        oc[ct] = MFMA16(pa, *(const bf16x8*)vp, oc[ct]);
      }
    }
  }

  int orow = b * S_LEN + q0 + wv * 16 + quad * 4;
  #pragma unroll
  for (int ct = 0; ct < 4; ++ct) {
    int col = hh * HDIM + ct * 16 + l15;
    #pragma unroll
    for (int r = 0; r < 4; ++r)
      ctx[(size_t)(orow + r) * HID + col] = (__bf16)oc[ct][r];
  }
}

// ---------------------------------------------------------------------------
// launch
// ---------------------------------------------------------------------------
extern "C" void kernel_launch(void* const* d_in, const int* in_sizes, int n_in,
                              void* d_out, int out_size, void* d_ws, size_t ws_size,
                              hipStream_t stream) {
  const int*   input_ids = (const int*)d_in[0];
  const int*   type_ids  = (const int*)d_in[1];
  const float* word_emb  = (const float*)d_in[2];
  const float* pos_emb   = (const float*)d_in[3];
  const float* type_emb  = (const float*)d_in[4];
  const float* eln_s     = (const float*)d_in[5];
  const float* eln_b     = (const float*)d_in[6];
  const float* wq = (const float*)d_in[7];
  const float* bq = (const float*)d_in[8];
  const float* wk = (const float*)d_in[9];
  const float* bk = (const float*)d_in[10];
  const float* wv = (const float*)d_in[11];
  const float* bv = (const float*)d_in[12];
  const float* wo = (const float*)d_in[13];
  const float* bo = (const float*)d_in[14];
  const float* l1s = (const float*)d_in[15];
  const float* l1b = (const float*)d_in[16];
  const float* w1  = (const float*)d_in[17];
  const float* b1  = (const float*)d_in[18];
  const float* w2  = (const float*)d_in[19];
  const float* b2  = (const float*)d_in[20];
  const float* l2s = (const float*)d_in[21];
  const float* l2b = (const float*)d_in[22];

  // ---- workspace carve-up ----
  char* p = (char*)d_ws;
  float*   h32    = (float*)p;            p += (size_t)NTOK * HID * 4;
  float*   tmp32  = (float*)p;            p += (size_t)NTOK * HID * 4 * 2; // p0,p1
  float*   tmp32b = tmp32 + (size_t)NTOK * HID;   // split-K partial 1
  __bf16*  vT16   = (__bf16*)tmp32;       // alias: vT live only during attn
  __bf16*  h16    = (__bf16*)p;           p += (size_t)NTOK * HID * 2;
  __bf16*  qkv16  = (__bf16*)p;           p += (size_t)NTOK * QKVN * 2;
  __bf16*  ctx16  = (__bf16*)p;           p += (size_t)NTOK * HID * 2;
  __bf16*  ffn16  = qkv16;                // alias qkv16+ctx16 contiguously
  float*   qkvb12 = (float*)p;            p += (size_t)NLAYER * QKVN * 4;
  float*   mb     = (float*)p;            p += (size_t)NTOK * 4;

  const size_t WHH = (size_t)HID * HID;
  const size_t WHF = (size_t)HID * FFN_DIM;
  const size_t WQKV = (size_t)QKVN * HID;

  // weight buffers: batched over all layers if ws is big enough
  size_t used = (size_t)(p - (char*)d_ws);
  size_t needB = used + (WQKV + WHH + 2 * WHF) * 2 * NLAYER + 256;
  int batched = (ws_size >= needB) ? 1 : 0;
  int nl = batched ? NLAYER : 1;
  __bf16* wTall  = (__bf16*)p;  p += WQKV * 2 * nl;
  __bf16* woTall = (__bf16*)p;  p += WHH * 2 * nl;
  __bf16* w1Tall = (__bf16*)p;  p += WHF * 2 * nl;
  __bf16* w2Tall = (__bf16*)p;  p += WHF * 2 * nl;
  size_t sQKV = batched ? WQKV : 0, sHH = batched ? WHH : 0,
         sHF = batched ? WHF : 0;

  dim3 blk(256), blk512(512);
  mask_kernel<<<dim3(NTOK / 256), blk, 0, stream>>>(input_ids, mb);
  pack_qkvb_kernel<<<dim3((NLAYER * QKVN + 255) / 256), blk, 0, stream>>>(
      bq, bk, bv, qkvb12);
  embed_ln_kernel<<<dim3(NTOK), blk, 0, stream>>>(
      input_ids, type_ids, word_emb, pos_emb, type_emb, eln_s, eln_b, h32, h16);

  if (batched) {
    tcvt4_kernel<<<dim3(HID / 32, HID / 32, 4 * NLAYER), blk, 0, stream>>>(
        wq, wk, wv, wo, wTall, woTall);
    tcvt_kernel<<<dim3(FFN_DIM / 32, HID / 32, NLAYER), blk, 0, stream>>>(
        w1, w1Tall, HID, FFN_DIM);
    tcvt_kernel<<<dim3(HID / 32, FFN_DIM / 32, NLAYER), blk, 0, stream>>>(
        w2, w2Tall, FFN_DIM, HID);
  }

  dim3 g_qkv(QKVN / 256, NTOK / 256, 1);      // 9 x 16 (256^2 8-phase)
  dim3 g_ff1(FFN_DIM / 256, NTOK / 256, 1);   // 12 x 16 (256^2 8-phase)
  dim3 g_wo(HID / 64, NTOK / 128, 1);         // 12 x 32
  dim3 g_ff2(HID / 64, NTOK / 128, 2);        // 12 x 32 x 2 (split-K)
  dim3 g_at(S_LEN / 64, NHEAD, 8);            // 8 x 12 x 8

  for (int l = 0; l < NLAYER; ++l) {
    size_t boff = (size_t)l * HID;
    if (!batched) {
      tcvt4_kernel<<<dim3(HID / 32, HID / 32, 4), blk, 0, stream>>>(
          wq + l * WHH, wk + l * WHH, wv + l * WHH, wo + l * WHH,
          wTall, woTall);
      tcvt_kernel<<<dim3(FFN_DIM / 32, HID / 32, 1), blk, 0, stream>>>(
          w1 + l * WHF, w1Tall, HID, FFN_DIM);
      tcvt_kernel<<<dim3(HID / 32, FFN_DIM / 32, 1), blk, 0, stream>>>(
          w2 + l * WHF, w2Tall, FFN_DIM, HID);
    }
    const __bf16* wTl  = wTall  + (size_t)l * sQKV;
    const __bf16* woTl = woTall + (size_t)l * sHH;
    const __bf16* w1Tl = w1Tall + (size_t)l * sHF;
    const __bf16* w2Tl = w2Tall + (size_t)l * sHF;

    // QKV (256^2 8-phase) with fused V-transpose into vT16
    mfma_gemm256<3><<<g_qkv, blk512, 0, stream>>>(
        h16, wTl, qkvb12 + (size_t)l * QKVN, qkv16, vT16,
        NTOK, QKVN, HID);
    attn_mfma<<<g_at, blk, 0, stream>>>(qkv16, vT16, mb, ctx16);
    mfma_gemm<0, 64><<<g_wo, blk, 0, stream>>>(
        ctx16, woTl, bo + boff, tmp32, nullptr, NTOK, HID, HID, HID);
    add_ln_kernel<<<dim3(NTOK), blk, 0, stream>>>(
        h32, tmp32, nullptr, l1s + boff, l1b + boff, h32, h16);
    // FFN1 (256^2 8-phase) with fused exact GELU
    mfma_gemm256<2><<<g_ff1, blk512, 0, stream>>>(
        h16, w1Tl, b1 + (size_t)l * FFN_DIM, ffn16, nullptr,
        NTOK, FFN_DIM, HID);
    // FFN2 split-K=2: partials in tmp32 / tmp32b, summed in add_ln
    mfma_gemm<0, 64><<<g_ff2, blk, 0, stream>>>(
        ffn16, w2Tl, b2 + boff, tmp32, nullptr, NTOK, HID, FFN_DIM,
        FFN_DIM / 2);
    float* dst = (l == NLAYER - 1) ? (float*)d_out : h32;
    add_ln_kernel<<<dim3(NTOK), blk, 0, stream>>>(
        h32, tmp32, tmp32b, l2s + boff, l2b + boff, dst, h16);
  }
}

// Round 4
// 2657.632 us; speedup vs baseline: 1.0700x; 1.0700x over previous
//
#include <hip/hip_runtime.h>
#include <hip/hip_bf16.h>
#include <math.h>

// ---- problem constants (BERT-base, B=8, S=512) ----
#define S_LEN   512
#define HID     768
#define NLAYER  12
#define NHEAD   12
#define FFN_DIM 3072
#define HDIM    64
#define NTOK    4096   // B*S
#define QKVN    2304   // 3*HID

typedef __bf16 bf16x8 __attribute__((ext_vector_type(8)));
typedef __bf16 bf16x4 __attribute__((ext_vector_type(4)));
typedef float  f32x4  __attribute__((ext_vector_type(4)));

typedef __attribute__((address_space(1))) const unsigned int gas_u32;
typedef __attribute__((address_space(3))) unsigned int las_u32;

#define MFMA16(a, b, c) __builtin_amdgcn_mfma_f32_16x16x32_bf16((a), (b), (c), 0, 0, 0)

// log2(e) and 0.125*log2(e) for exp2-domain softmax
#define L2E      1.4426950408889634f
#define QK_SCALE 0.18033688011112042f

// ---------------------------------------------------------------------------
// fast exact-erf GELU: A&S 7.1.26, max abs err 1.5e-7 (invisible in bf16).
// ---------------------------------------------------------------------------
__device__ __forceinline__ float fast_gelu(float v) {
  float ax = fabsf(v) * 0.70710678118654752f;
  float t  = __builtin_amdgcn_rcpf(fmaf(0.3275911f, ax, 1.0f));
  float p  = fmaf(fmaf(fmaf(fmaf(1.061405429f, t, -1.453152027f), t,
                            1.421413741f), t, -0.284496736f), t, 0.254829592f);
  float e  = __expf(-ax * ax);
  float er = 1.0f - p * t * e;
  er = copysignf(er, v);
  return 0.5f * v * (1.0f + er);
}

// ---------------------------------------------------------------------------
// block-wide reduction of (sum, sumsq) over 256 threads (4 waves of 64)
// ---------------------------------------------------------------------------
__device__ __forceinline__ void block_reduce_2(float& sum, float& sq) {
  __shared__ float sd[8];
  int lane = threadIdx.x & 63;
  int wid  = threadIdx.x >> 6;
  #pragma unroll
  for (int off = 32; off > 0; off >>= 1) {
    sum += __shfl_down(sum, off, 64);
    sq  += __shfl_down(sq,  off, 64);
  }
  if (lane == 0) { sd[wid] = sum; sd[4 + wid] = sq; }
  __syncthreads();
  sum = sd[0] + sd[1] + sd[2] + sd[3];
  sq  = sd[4] + sd[5] + sd[6] + sd[7];
}

// ---------------------------------------------------------------------------
// mask bias, pre-scaled into exp2 domain: -10000*log2e where id==0, else 0
// ---------------------------------------------------------------------------
__global__ __launch_bounds__(256) void mask_kernel(const int* __restrict__ ids,
                                                   float* __restrict__ mb) {
  int i = blockIdx.x * 256 + threadIdx.x;
  if (i < NTOK) mb[i] = (ids[i] == 0) ? (-10000.0f * L2E) : 0.0f;
}

// ---------------------------------------------------------------------------
// pack q/k/v biases for ALL layers into [L][2304] once
// ---------------------------------------------------------------------------
__global__ __launch_bounds__(256) void pack_qkvb_kernel(
    const float* __restrict__ bq, const float* __restrict__ bk,
    const float* __restrict__ bv, float* __restrict__ out) {
  int i = blockIdx.x * 256 + threadIdx.x;
  if (i >= NLAYER * QKVN) return;
  int l = i / QKVN, c = i % QKVN;
  float v = (c < HID) ? bq[l * HID + c]
          : (c < 2 * HID) ? bk[l * HID + c - HID]
                          : bv[l * HID + c - 2 * HID];
  out[i] = v;
}

// ---------------------------------------------------------------------------
// embeddings + layernorm -> fp32 h and bf16 h
// ---------------------------------------------------------------------------
__global__ __launch_bounds__(256) void embed_ln_kernel(
    const int* __restrict__ ids, const int* __restrict__ tids,
    const float* __restrict__ we, const float* __restrict__ pe,
    const float* __restrict__ te, const float* __restrict__ gamma,
    const float* __restrict__ beta, float* __restrict__ out32,
    __bf16* __restrict__ out16) {
  int t = blockIdx.x;
  int s = t & (S_LEN - 1);
  int id = ids[t];
  int tp = tids[t];
  float x[3];
  #pragma unroll
  for (int i = 0; i < 3; ++i) {
    int c = threadIdx.x + i * 256;
    x[i] = we[(size_t)id * HID + c] + pe[(size_t)s * HID + c] +
           te[(size_t)tp * HID + c];
  }
  float sum = x[0] + x[1] + x[2];
  float sq  = x[0]*x[0] + x[1]*x[1] + x[2]*x[2];
  block_reduce_2(sum, sq);
  float mu   = sum * (1.0f / HID);
  float var  = sq * (1.0f / HID) - mu * mu;
  float rstd = rsqrtf(var + 1e-12f);
  #pragma unroll
  for (int i = 0; i < 3; ++i) {
    int c = threadIdx.x + i * 256;
    float v = (x[i] - mu) * rstd * gamma[c] + beta[c];
    out32[(size_t)t * HID + c] = v;
    out16[(size_t)t * HID + c] = (__bf16)v;
  }
}

// ---------------------------------------------------------------------------
// residual add (+ optional third partial) + layernorm -> fp32 and bf16
// ---------------------------------------------------------------------------
__global__ __launch_bounds__(256) void add_ln_kernel(
    const float* __restrict__ a, const float* __restrict__ b,
    const float* __restrict__ c,
    const float* __restrict__ gamma, const float* __restrict__ beta,
    float* __restrict__ out32, __bf16* __restrict__ out16) {
  int t = blockIdx.x;
  float x[3];
  #pragma unroll
  for (int i = 0; i < 3; ++i) {
    int ci = threadIdx.x + i * 256;
    size_t idx = (size_t)t * HID + ci;
    x[i] = a[idx] + b[idx];
    if (c) x[i] += c[idx];
  }
  float sum = x[0] + x[1] + x[2];
  float sq  = x[0]*x[0] + x[1]*x[1] + x[2]*x[2];
  block_reduce_2(sum, sq);
  float mu   = sum * (1.0f / HID);
  float var  = sq * (1.0f / HID) - mu * mu;
  float rstd = rsqrtf(var + 1e-12f);
  #pragma unroll
  for (int i = 0; i < 3; ++i) {
    int ci = threadIdx.x + i * 256;
    float v = (x[i] - mu) * rstd * gamma[ci] + beta[ci];
    out32[(size_t)t * HID + ci] = v;
    out16[(size_t)t * HID + ci] = (__bf16)v;
  }
}

// ---------------------------------------------------------------------------
// transpose + fp32->bf16: src [R][C] f32 -> dst [C][R] bf16. blockIdx.z=layer.
// ---------------------------------------------------------------------------
__global__ __launch_bounds__(256) void tcvt_kernel(
    const float* __restrict__ src, __bf16* __restrict__ dst, int R, int C) {
  __shared__ float tile[32][33];
  int l = blockIdx.z;
  src += (size_t)l * R * C;
  dst += (size_t)l * R * C;
  int c0 = blockIdx.x * 32, r0 = blockIdx.y * 32;
  int tx = threadIdx.x & 31, ty = threadIdx.x >> 5;  // ty 0..7
  #pragma unroll
  for (int i = 0; i < 4; ++i) {
    int r = ty + i * 8;
    tile[r][tx] = src[(size_t)(r0 + r) * C + c0 + tx];
  }
  __syncthreads();
  #pragma unroll
  for (int i = 0; i < 4; ++i) {
    int r = ty + i * 8;
    dst[(size_t)(c0 + r) * R + r0 + tx] = (__bf16)tile[tx][r];
  }
}

// 4 HxH transposes (wq,wk,wv,wo), blockIdx.z = layer*4 + sel.
__global__ __launch_bounds__(256) void tcvt4_kernel(
    const float* __restrict__ sq, const float* __restrict__ sk,
    const float* __restrict__ sv, const float* __restrict__ so,
    __bf16* __restrict__ dqkv, __bf16* __restrict__ dwo) {
  __shared__ float tile[32][33];
  const size_t WHH = (size_t)HID * HID;
  int z = blockIdx.z;
  int l = z >> 2, sel = z & 3;
  const float* src = ((sel == 0) ? sq : (sel == 1) ? sk : (sel == 2) ? sv : so)
                     + (size_t)l * WHH;
  __bf16* dst = (sel < 3) ? dqkv + (size_t)l * 3 * WHH + (size_t)sel * WHH
                          : dwo + (size_t)l * WHH;
  int c0 = blockIdx.x * 32, r0 = blockIdx.y * 32;
  int tx = threadIdx.x & 31, ty = threadIdx.x >> 5;
  #pragma unroll
  for (int i = 0; i < 4; ++i) {
    int r = ty + i * 8;
    tile[r][tx] = src[(size_t)(r0 + r) * HID + c0 + tx];
  }
  __syncthreads();
  #pragma unroll
  for (int i = 0; i < 4; ++i) {
    int r = ty + i * 8;
    dst[(size_t)(c0 + r) * HID + r0 + tx] = (__bf16)tile[tx][r];
  }
}

// ---------------------------------------------------------------------------
// m97-style bf16 MFMA GEMM: C[M,N] = A[M,K] @ Bt[N,K]^T + bias.
// 128xTN tile (TN=128 or 64), BK=64, 256 threads.
//   TN=128: waves 2x2, each 64x64 (4x4 frags).  TN=64: waves 4x1, each 32x64.
// Staging: global_load_lds 16B, XOR swizzle on the GLOBAL source address
// (LDS dest is wave-uniform + lane*16), so frag ds_read_b128 is 2-way (free).
// MODE 0: f32 out (split-K via blockIdx.z: chunk kz covers K rows
//         [kz*kchunk,(kz+1)*kchunk), partial kz -> Cout + kz*M*N, bias kz==0);
// MODE 1: bf16 out; MODE 2: bf16 out + fast exact GELU;
// MODE 3: bf16 out, V-cols (>=1536) -> vt[b][h][d][s] (fused V-transpose).
// ---------------------------------------------------------------------------
template <int MODE, int TN>
__global__ __launch_bounds__(256) void mfma_gemm(
    const __bf16* __restrict__ A, const __bf16* __restrict__ Bt,
    const float* __restrict__ bias, void* __restrict__ Cout,
    __bf16* __restrict__ vtout, int M, int N, int K, int kchunk) {
  constexpr int AI = 4;
  constexpr int BI = TN / 32;
  constexpr int RT = (TN == 128) ? 4 : 2;
  constexpr int CT = 4;
  __shared__ __align__(16) __bf16 As[128 * 64];
  __shared__ __align__(16) __bf16 Bs[TN * 64];
  const int tid = threadIdx.x;
  const int w = tid >> 6, lane = tid & 63;
  const int l15 = lane & 15, quad = lane >> 4;
  const int m0 = blockIdx.y * 128, n0 = blockIdx.x * TN;
  const int kz = blockIdx.z;
  const int lr = lane >> 3;
  const int colg = (lane & 7) ^ lr;

  const int wr = (TN == 128) ? (w >> 1) * 64 : w * 32;
  const int wc = (TN == 128) ? (w & 1) * 64 : 0;

  A  += (size_t)kz * kchunk;
  Bt += (size_t)kz * kchunk;

  f32x4 acc[RT][CT];
  const f32x4 z4 = {0.f, 0.f, 0.f, 0.f};
  #pragma unroll
  for (int i = 0; i < RT; ++i)
    #pragma unroll
    for (int j = 0; j < CT; ++j) acc[i][j] = z4;

  const __bf16* Ag = A  + (size_t)(m0 + 8 * AI * w + lr) * K + colg * 8;
  const __bf16* Bg = Bt + (size_t)(n0 + 8 * BI * w + lr) * K + colg * 8;
  __bf16* Al = As + 512 * AI * w;
  __bf16* Bl = Bs + 512 * BI * w;

  for (int kt = 0; kt < kchunk; kt += 64) {
    #pragma unroll
    for (int i = 0; i < AI; ++i)
      __builtin_amdgcn_global_load_lds(
          (gas_u32*)(Ag + (size_t)(8 * i) * K + kt),
          (las_u32*)(Al + 512 * i), 16, 0, 0);
    #pragma unroll
    for (int i = 0; i < BI; ++i)
      __builtin_amdgcn_global_load_lds(
          (gas_u32*)(Bg + (size_t)(8 * i) * K + kt),
          (las_u32*)(Bl + 512 * i), 16, 0, 0);
    __syncthreads();
    #pragma unroll
    for (int kc = 0; kc < 2; ++kc) {
      bf16x8 af[RT], bfr[CT];
      #pragma unroll
      for (int rt = 0; rt < RT; ++rt) {
        int row = wr + rt * 16 + l15;
        af[rt] = *(const bf16x8*)&As[(row * 8 + ((kc * 4 + quad) ^ (row & 7))) * 8];
      }
      #pragma unroll
      for (int ct = 0; ct < CT; ++ct) {
        int col = wc + ct * 16 + l15;
        bfr[ct] = *(const bf16x8*)&Bs[(col * 8 + ((kc * 4 + quad) ^ (col & 7))) * 8];
      }
      #pragma unroll
      for (int rt = 0; rt < RT; ++rt)
        #pragma unroll
        for (int ct = 0; ct < CT; ++ct)
          acc[rt][ct] = MFMA16(af[rt], bfr[ct], acc[rt][ct]);
    }
    __syncthreads();
  }

  float* outf = (float*)Cout + (size_t)kz * M * N;
  #pragma unroll
  for (int rt = 0; rt < RT; ++rt) {
    int rbase = m0 + wr + rt * 16 + quad * 4;
    #pragma unroll
    for (int ct = 0; ct < CT; ++ct) {
      int col = n0 + wc + ct * 16 + l15;
      float bv = (kz == 0) ? bias[col] : 0.0f;
      float vv[4];
      #pragma unroll
      for (int r = 0; r < 4; ++r) {
        float v = acc[rt][ct][r] + bv;
        if (MODE == 2) v = fast_gelu(v);
        vv[r] = v;
      }
      if (MODE == 3 && col >= 2 * HID) {
        int cc = col - 2 * HID;
        int hh = cc >> 6, d = cc & 63;
        int bb = rbase >> 9, s0 = rbase & (S_LEN - 1);
        bf16x4 pk = {(__bf16)vv[0], (__bf16)vv[1], (__bf16)vv[2], (__bf16)vv[3]};
        *(bf16x4*)(vtout +
                   (((size_t)(bb * NHEAD + hh) * HDIM + d) * S_LEN + s0)) = pk;
      } else {
        #pragma unroll
        for (int r = 0; r < 4; ++r) {
          if (MODE == 0)
            outf[(size_t)(rbase + r) * N + col] = vv[r];
          else
            ((__bf16*)Cout)[(size_t)(rbase + r) * N + col] = (__bf16)vv[r];
        }
      }
    }
  }
}

// ---------------------------------------------------------------------------
// MFMA attention. 1D grid (768 blocks), XCD-grouped decode: blocks with the
// same batch b land on the same XCD (hw maps linear id i -> XCD i%8), so K/V
// panels (1.5 MB/batch) stay in one XCD's L2 instead of 8x duplication.
// Softmax in exp2 domain (scale 0.125*log2e folded in, mask pre-scaled);
// 1/sum folded into the 16 output multiplies instead of 128 P-stores.
// ---------------------------------------------------------------------------
__global__ __launch_bounds__(256) void attn_mfma(
    const __bf16* __restrict__ qkv,  // [tok][2304], q at +0, k at +768
    const __bf16* __restrict__ vt,   // [b][h][64][512]
    const float* __restrict__ mb,    // [B*S], already * log2e
    __bf16* __restrict__ ctx) {      // [tok][768]
  constexpr int PLD = 264;
  __shared__ __align__(16) __bf16 Plds[4][16 * PLD];
  const int tid = threadIdx.x;
  const int wv = tid >> 6, lane = tid & 63;
  const int l15 = lane & 15, quad = lane >> 4;
  // XCD-grouped decode: i%8 = XCD slot; XCD x owns batch x (12h x 8q blocks)
  const int i = blockIdx.x;
  const int xcd = i & 7, s = i >> 3;
  const int b = xcd, hh = s >> 3, q0 = (s & 7) * 64;
  const f32x4 z4 = {0.f, 0.f, 0.f, 0.f};

  size_t qoff = ((size_t)(b * S_LEN) + q0 + wv * 16 + l15) * QKVN + hh * HDIM;
  bf16x8 qa0 = *(const bf16x8*)(qkv + qoff + quad * 8);
  bf16x8 qa1 = *(const bf16x8*)(qkv + qoff + 32 + quad * 8);

  f32x4 sc[32];
  #pragma unroll
  for (int kt = 0; kt < 32; ++kt) {
    size_t koff = ((size_t)(b * S_LEN) + kt * 16 + l15) * QKVN + HID + hh * HDIM;
    bf16x8 kb0 = *(const bf16x8*)(qkv + koff + quad * 8);
    bf16x8 kb1 = *(const bf16x8*)(qkv + koff + 32 + quad * 8);
    f32x4 t = MFMA16(qa0, kb0, z4);
    sc[kt] = MFMA16(qa1, kb1, t);
  }

  float mx[4] = {-1e30f, -1e30f, -1e30f, -1e30f};
  #pragma unroll
  for (int kt = 0; kt < 32; ++kt) {
    float mval = mb[b * S_LEN + kt * 16 + l15];
    #pragma unroll
    for (int r = 0; r < 4; ++r) {
      float x = fmaf(sc[kt][r], QK_SCALE, mval);  // exp2 domain
      sc[kt][r] = x;
      mx[r] = fmaxf(mx[r], x);
    }
  }
  #pragma unroll
  for (int m = 1; m < 16; m <<= 1)
    #pragma unroll
    for (int r = 0; r < 4; ++r) mx[r] = fmaxf(mx[r], __shfl_xor(mx[r], m, 64));

  float sm[4] = {0.f, 0.f, 0.f, 0.f};
  #pragma unroll
  for (int kt = 0; kt < 32; ++kt)
    #pragma unroll
    for (int r = 0; r < 4; ++r) {
      float e = exp2f(sc[kt][r] - mx[r]);
      sc[kt][r] = e;
      sm[r] += e;
    }
  #pragma unroll
  for (int m = 1; m < 16; m <<= 1)
    #pragma unroll
    for (int r = 0; r < 4; ++r) sm[r] += __shfl_xor(sm[r], m, 64);
  float inv[4];
  #pragma unroll
  for (int r = 0; r < 4; ++r) inv[r] = 1.0f / sm[r];

  __bf16* pbuf = &Plds[wv][0];
  const __bf16* vbase = vt + (size_t)(b * NHEAD + hh) * HDIM * S_LEN;
  f32x4 oc[4] = {z4, z4, z4, z4};
  #pragma unroll
  for (int half = 0; half < 2; ++half) {
    #pragma unroll
    for (int kt2 = 0; kt2 < 16; ++kt2) {
      int kt = half * 16 + kt2;
      #pragma unroll
      for (int r = 0; r < 4; ++r)
        pbuf[(quad * 4 + r) * PLD + kt2 * 16 + l15] = (__bf16)sc[kt][r];
    }
    #pragma unroll
    for (int kc = 0; kc < 8; ++kc) {
      bf16x8 pa = *(const bf16x8*)&pbuf[l15 * PLD + kc * 32 + quad * 8];
      int kbase = half * 256 + kc * 32;
      #pragma unroll
      for (int ct = 0; ct < 4; ++ct) {
        const __bf16* vp =
            vbase + (size_t)(ct * 16 + l15) * S_LEN + kbase + quad * 8;
        oc[ct] = MFMA16(pa, *(const bf16x8*)vp, oc[ct]);
      }
    }
  }

  int orow = b * S_LEN + q0 + wv * 16 + quad * 4;
  #pragma unroll
  for (int ct = 0; ct < 4; ++ct) {
    int col = hh * HDIM + ct * 16 + l15;
    #pragma unroll
    for (int r = 0; r < 4; ++r)
      ctx[(size_t)(orow + r) * HID + col] = (__bf16)(oc[ct][r] * inv[r]);
  }
}

// ---------------------------------------------------------------------------
// launch
// ---------------------------------------------------------------------------
extern "C" void kernel_launch(void* const* d_in, const int* in_sizes, int n_in,
                              void* d_out, int out_size, void* d_ws, size_t ws_size,
                              hipStream_t stream) {
  const int*   input_ids = (const int*)d_in[0];
  const int*   type_ids  = (const int*)d_in[1];
  const float* word_emb  = (const float*)d_in[2];
  const float* pos_emb   = (const float*)d_in[3];
  const float* type_emb  = (const float*)d_in[4];
  const float* eln_s     = (const float*)d_in[5];
  const float* eln_b     = (const float*)d_in[6];
  const float* wq = (const float*)d_in[7];
  const float* bq = (const float*)d_in[8];
  const float* wk = (const float*)d_in[9];
  const float* bk = (const float*)d_in[10];
  const float* wv = (const float*)d_in[11];
  const float* bv = (const float*)d_in[12];
  const float* wo = (const float*)d_in[13];
  const float* bo = (const float*)d_in[14];
  const float* l1s = (const float*)d_in[15];
  const float* l1b = (const float*)d_in[16];
  const float* w1  = (const float*)d_in[17];
  const float* b1  = (const float*)d_in[18];
  const float* w2  = (const float*)d_in[19];
  const float* b2  = (const float*)d_in[20];
  const float* l2s = (const float*)d_in[21];
  const float* l2b = (const float*)d_in[22];

  // ---- workspace carve-up ----
  char* p = (char*)d_ws;
  float*   h32    = (float*)p;            p += (size_t)NTOK * HID * 4;
  float*   tmp32  = (float*)p;            p += (size_t)NTOK * HID * 4 * 2; // p0,p1
  float*   tmp32b = tmp32 + (size_t)NTOK * HID;   // split-K partial 1
  __bf16*  vT16   = (__bf16*)tmp32;       // alias: vT live only during attn
  __bf16*  h16    = (__bf16*)p;           p += (size_t)NTOK * HID * 2;
  __bf16*  qkv16  = (__bf16*)p;           p += (size_t)NTOK * QKVN * 2;
  __bf16*  ctx16  = (__bf16*)p;           p += (size_t)NTOK * HID * 2;
  __bf16*  ffn16  = qkv16;                // alias qkv16+ctx16 contiguously
  float*   qkvb12 = (float*)p;            p += (size_t)NLAYER * QKVN * 4;
  float*   mb     = (float*)p;            p += (size_t)NTOK * 4;

  const size_t WHH = (size_t)HID * HID;
  const size_t WHF = (size_t)HID * FFN_DIM;
  const size_t WQKV = (size_t)QKVN * HID;

  // weight buffers: batched over all layers if ws is big enough
  size_t used = (size_t)(p - (char*)d_ws);
  size_t needB = used + (WQKV + WHH + 2 * WHF) * 2 * NLAYER + 256;
  int batched = (ws_size >= needB) ? 1 : 0;
  int nl = batched ? NLAYER : 1;
  __bf16* wTall  = (__bf16*)p;  p += WQKV * 2 * nl;
  __bf16* woTall = (__bf16*)p;  p += WHH * 2 * nl;
  __bf16* w1Tall = (__bf16*)p;  p += WHF * 2 * nl;
  __bf16* w2Tall = (__bf16*)p;  p += WHF * 2 * nl;
  size_t sQKV = batched ? WQKV : 0, sHH = batched ? WHH : 0,
         sHF = batched ? WHF : 0;

  dim3 blk(256);
  mask_kernel<<<dim3(NTOK / 256), blk, 0, stream>>>(input_ids, mb);
  pack_qkvb_kernel<<<dim3((NLAYER * QKVN + 255) / 256), blk, 0, stream>>>(
      bq, bk, bv, qkvb12);
  embed_ln_kernel<<<dim3(NTOK), blk, 0, stream>>>(
      input_ids, type_ids, word_emb, pos_emb, type_emb, eln_s, eln_b, h32, h16);

  if (batched) {
    tcvt4_kernel<<<dim3(HID / 32, HID / 32, 4 * NLAYER), blk, 0, stream>>>(
        wq, wk, wv, wo, wTall, woTall);
    tcvt_kernel<<<dim3(FFN_DIM / 32, HID / 32, NLAYER), blk, 0, stream>>>(
        w1, w1Tall, HID, FFN_DIM);
    tcvt_kernel<<<dim3(HID / 32, FFN_DIM / 32, NLAYER), blk, 0, stream>>>(
        w2, w2Tall, FFN_DIM, HID);
  }

  dim3 g_qkv(QKVN / 128, NTOK / 128, 1);      // 18 x 32
  dim3 g_ff1(FFN_DIM / 128, NTOK / 128, 1);   // 24 x 32
  dim3 g_wo(HID / 64, NTOK / 128, 2);         // 12 x 32 x 2 (split-K)
  dim3 g_ff2(HID / 64, NTOK / 128, 2);        // 12 x 32 x 2 (split-K)
  dim3 g_at(8 * NHEAD * 8, 1, 1);             // 768, XCD-grouped decode

  for (int l = 0; l < NLAYER; ++l) {
    size_t boff = (size_t)l * HID;
    if (!batched) {
      tcvt4_kernel<<<dim3(HID / 32, HID / 32, 4), blk, 0, stream>>>(
          wq + l * WHH, wk + l * WHH, wv + l * WHH, wo + l * WHH,
          wTall, woTall);
      tcvt_kernel<<<dim3(FFN_DIM / 32, HID / 32, 1), blk, 0, stream>>>(
          w1 + l * WHF, w1Tall, HID, FFN_DIM);
      tcvt_kernel<<<dim3(HID / 32, FFN_DIM / 32, 1), blk, 0, stream>>>(
          w2 + l * WHF, w2Tall, FFN_DIM, HID);
    }
    const __bf16* wTl  = wTall  + (size_t)l * sQKV;
    const __bf16* woTl = woTall + (size_t)l * sHH;
    const __bf16* w1Tl = w1Tall + (size_t)l * sHF;
    const __bf16* w2Tl = w2Tall + (size_t)l * sHF;

    // QKV with fused V-transpose into vT16
    mfma_gemm<3, 128><<<g_qkv, blk, 0, stream>>>(
        h16, wTl, qkvb12 + (size_t)l * QKVN, qkv16, vT16,
        NTOK, QKVN, HID, HID);
    attn_mfma<<<g_at, blk, 0, stream>>>(qkv16, vT16, mb, ctx16);
    // WO split-K=2: partials in tmp32 / tmp32b, summed in add_ln
    mfma_gemm<0, 64><<<g_wo, blk, 0, stream>>>(
        ctx16, woTl, bo + boff, tmp32, nullptr, NTOK, HID, HID, HID / 2);
    add_ln_kernel<<<dim3(NTOK), blk, 0, stream>>>(
        h32, tmp32, tmp32b, l1s + boff, l1b + boff, h32, h16);
    // FFN1 with fused exact GELU
    mfma_gemm<2, 128><<<g_ff1, blk, 0, stream>>>(
        h16, w1Tl, b1 + (size_t)l * FFN_DIM, ffn16, nullptr,
        NTOK, FFN_DIM, HID, HID);
    // FFN2 split-K=2: partials in tmp32 / tmp32b, summed in add_ln
    mfma_gemm<0, 64><<<g_ff2, blk, 0, stream>>>(
        ffn16, w2Tl, b2 + boff, tmp32, nullptr, NTOK, HID, FFN_DIM,
        FFN_DIM / 2);
    float* dst = (l == NLAYER - 1) ? (float*)d_out : h32;
    add_ln_kernel<<<dim3(NTOK), blk, 0, stream>>>(
        h32, tmp32, tmp32b, l2s + boff, l2b + boff, dst, h16);
  }
}